// Round 1
// baseline (588.152 us; speedup 1.0000x reference)
//
#include <hip/hip_runtime.h>

#define BLOCK 512
#define RPB   32          // rows per block-iteration
#define X1LD  260         // padded LDS row stride for x1 (breaks 4-way bank conflict)

__global__ __launch_bounds__(BLOCK) void tp_kernel(
    const float* __restrict__ x1, const float* __restrict__ x2,
    const float* __restrict__ w0, const float* __restrict__ w1,
    const float* __restrict__ w2, const float* __restrict__ w3,
    const float* __restrict__ w4,
    float* __restrict__ out, int n)
{
    __shared__ float lds_w[5 * 4096];        // 80 KB: Wss, Wvvs, Wsv, Wvs, Wvvv (natural [u][w])
    __shared__ float lds_x1[RPB * X1LD];     // ~33 KB
    __shared__ float lds_x2[RPB * 4];

    const int t = threadIdx.x;

    // ---- stage all 5 weight matrices once per block ----
    {
        const float* srcs[5] = {w0, w1, w2, w3, w4};
        #pragma unroll
        for (int m = 0; m < 5; ++m) {
            const float4* s = (const float4*)srcs[m];
            float4* d = (float4*)(&lds_w[m * 4096]);
            for (int i = t; i < 1024; i += BLOCK) d[i] = s[i];
        }
    }

    const int g = t & 15;    // output column group: w = 4g..4g+3
    const int r = t >> 4;    // local row 0..31

    const int nchunks = (n + RPB - 1) / RPB;
    for (int chunk = blockIdx.x; chunk < nchunks; chunk += (int)gridDim.x) {
        const int z0 = chunk * RPB;

        // ---- stage x1 (RPB rows x 256 floats), coalesced float4 ----
        for (int i = t; i < RPB * 64; i += BLOCK) {
            const int row = i >> 6;
            const int c4  = i & 63;
            const int z   = z0 + row;
            float4 v = make_float4(0.f, 0.f, 0.f, 0.f);
            if (z < n) v = *(const float4*)(x1 + (size_t)z * 256 + c4 * 4);
            *(float4*)(&lds_x1[row * X1LD + c4 * 4]) = v;
        }
        if (t < RPB * 4) {
            const int z = z0 + (t >> 2);
            lds_x2[t] = (z < n) ? x2[(size_t)z * 4 + (t & 3)] : 0.f;
        }
        __syncthreads();

        // ---- matvec accumulation over u ----
        float yss[4], ysv[4], yvvs[4][3], yvs[4][3], yvvv[4][3];
        #pragma unroll
        for (int j = 0; j < 4; ++j) {
            yss[j] = 0.f; ysv[j] = 0.f;
            #pragma unroll
            for (int i = 0; i < 3; ++i) { yvvs[j][i] = 0.f; yvs[j][i] = 0.f; yvvv[j][i] = 0.f; }
        }

        const float* xr = &lds_x1[r * X1LD];
        #pragma unroll 4
        for (int u = 0; u < 64; ++u) {
            alignas(16) float wss[4], wvvs[4], wsv[4], wvs[4], wvvv[4];
            *(float4*)wss  = *(const float4*)(&lds_w[0*4096 + u*64 + 4*g]);
            *(float4*)wvvs = *(const float4*)(&lds_w[1*4096 + u*64 + 4*g]);
            *(float4*)wsv  = *(const float4*)(&lds_w[2*4096 + u*64 + 4*g]);
            *(float4*)wvs  = *(const float4*)(&lds_w[3*4096 + u*64 + 4*g]);
            *(float4*)wvvv = *(const float4*)(&lds_w[4*4096 + u*64 + 4*g]);
            const float s1  = xr[u];
            const float v1x = xr[64 + 3*u + 0];
            const float v1y = xr[64 + 3*u + 1];
            const float v1z = xr[64 + 3*u + 2];
            #pragma unroll
            for (int j = 0; j < 4; ++j) {
                yss[j]     += wss[j]  * s1;
                ysv[j]     += wsv[j]  * s1;
                yvvs[j][0] += wvvs[j] * v1x;
                yvvs[j][1] += wvvs[j] * v1y;
                yvvs[j][2] += wvvs[j] * v1z;
                yvs[j][0]  += wvs[j]  * v1x;
                yvs[j][1]  += wvs[j]  * v1y;
                yvs[j][2]  += wvs[j]  * v1z;
                yvvv[j][0] += wvvv[j] * v1x;
                yvvv[j][1] += wvvv[j] * v1y;
                yvvv[j][2] += wvvv[j] * v1z;
            }
        }

        // ---- epilogue: fold in x2, write out ----
        const float a0  = 0.088388347648318447f;   // sqrt(1/(2*64))
        const float a1  = 0.072168783648703216f;   // sqrt(1/(3*64))
        const float is3 = 0.57735026918962576f;    // 1/sqrt(3)
        const float is2 = 0.70710678118654752f;    // 1/sqrt(2)
        const float s2  = lds_x2[r*4 + 0];
        const float v2x = lds_x2[r*4 + 1];
        const float v2y = lds_x2[r*4 + 2];
        const float v2z = lds_x2[r*4 + 3];
        const int z = z0 + r;
        if (z < n) {
            float* orow = out + (size_t)z * 256;
            alignas(16) float os[4];
            alignas(16) float ov[12];
            #pragma unroll
            for (int j = 0; j < 4; ++j) {
                os[j] = a0 * (yss[j]*s2 + is3*(yvvs[j][0]*v2x + yvvs[j][1]*v2y + yvvs[j][2]*v2z));
                const float cx = yvvv[j][1]*v2z - yvvv[j][2]*v2y;
                const float cy = yvvv[j][2]*v2x - yvvv[j][0]*v2z;
                const float cz = yvvv[j][0]*v2y - yvvv[j][1]*v2x;
                ov[3*j+0] = a1 * (ysv[j]*v2x + yvs[j][0]*s2 + is2*cx);
                ov[3*j+1] = a1 * (ysv[j]*v2y + yvs[j][1]*s2 + is2*cy);
                ov[3*j+2] = a1 * (ysv[j]*v2z + yvs[j][2]*s2 + is2*cz);
            }
            *(float4*)(orow + 4*g)           = *(float4*)os;        // out_s[4g..4g+3]
            *(float4*)(orow + 64 + 12*g + 0) = *(float4*)(ov + 0);  // out_v, w*3+k layout
            *(float4*)(orow + 64 + 12*g + 4) = *(float4*)(ov + 4);
            *(float4*)(orow + 64 + 12*g + 8) = *(float4*)(ov + 8);
        }
        __syncthreads();
    }
}

extern "C" void kernel_launch(void* const* d_in, const int* in_sizes, int n_in,
                              void* d_out, int out_size, void* d_ws, size_t ws_size,
                              hipStream_t stream) {
    const float* x1 = (const float*)d_in[0];
    const float* x2 = (const float*)d_in[1];
    const float* w0 = (const float*)d_in[2];   // w_ss_s
    const float* w1 = (const float*)d_in[3];   // w_vv_s
    const float* w2 = (const float*)d_in[4];   // w_sv_v
    const float* w3 = (const float*)d_in[5];   // w_vs_v
    const float* w4 = (const float*)d_in[6];   // w_vv_v
    float* out = (float*)d_out;
    const int n = in_sizes[0] / 256;
    tp_kernel<<<256, BLOCK, 0, stream>>>(x1, x2, w0, w1, w2, w3, w4, out, n);
}